// Round 7
// baseline (198.949 us; speedup 1.0000x reference)
//
#include <hip/hip_runtime.h>

// GraphSAGE: agg = segment_mean(x[src] -> dst); out = relu(x@Ws + bs + agg@Wn + bn)
// N=100000, D_IN=D_OUT=64, E=1600000
// Pipeline: [hist | x->bf16 | WT^T+bias fused] -> column scan -> partition
// (inline base-scan) -> per-bucket LDS counting sort (CSR, pre-shifted offsets)
// -> bf16 gather-aggregate (split in 2 for profiler visibility) -> MFMA GEMM.

#define D 64
#define P 512        // partition chunks
#define CVTB 1024    // cvt blocks fused behind hist blocks
#define WTB 4        // weight-transpose blocks
#define NBMAX 1024   // max buckets
#define BN 128       // nodes per bucket (dst >> 7)
#define SORTCAP 8160 // max edges staged per bucket (mean ~2046)
#define KP 136       // padded K pitch (bf16 elems) for MFMA LDS tiles

typedef __attribute__((ext_vector_type(8))) short bf8_t;
typedef __attribute__((ext_vector_type(4))) float f4_t;
typedef __attribute__((ext_vector_type(2))) float f2_t;

__device__ inline unsigned int bf_rn(float f) {  // fp32 -> bf16 (RNE)
  unsigned int u = __float_as_uint(f);
  return (u + 0x7FFFu + ((u >> 16) & 1u)) >> 16;
}
__device__ inline unsigned int packbf2(float a, float b) {
  return bf_rn(a) | (bf_rn(b) << 16);
}

// ---------- pass 1 (fused): bucket histogram | x->bf16 | WT transpose ------
__global__ __launch_bounds__(256) void pre_k(const int* __restrict__ dst,
                                             int* __restrict__ hist,
                                             int E, int chunk, int nb,
                                             const float* __restrict__ x,
                                             unsigned short* __restrict__ xbf,
                                             int total4,
                                             const float* __restrict__ Ws,
                                             const float* __restrict__ Wn,
                                             const float* __restrict__ bs,
                                             const float* __restrict__ bn,
                                             unsigned short* __restrict__ wtbf,
                                             float* __restrict__ biasf) {
  __shared__ int h[NBMAX];
  int p = blockIdx.x;
  int t = threadIdx.x;
  if (p < P) {
    for (int i = t; i < nb; i += 256) h[i] = 0;
    __syncthreads();
    int s = p * chunk, e = min(E, s + chunk);
    for (int i = s + t; i < e; i += 256) atomicAdd(&h[dst[i] >> 7], 1);
    __syncthreads();
    for (int i = t; i < nb; i += 256) hist[p * nb + i] = h[i];
  } else if (p < P + CVTB) {
    int i = (p - P) * 256 + t;
    int stride = CVTB * 256;
    for (; i < total4; i += stride) {
      float4 v = ((const float4*)x)[i];
      uint2 r;
      r.x = packbf2(v.x, v.y);
      r.y = packbf2(v.z, v.w);
      ((uint2*)xbf)[i] = r;
    }
  } else {
    // WT[j][k] = W_cat[k][j] in bf16, K=128; plus fused bias
    int idx = (p - P - CVTB) * 256 + t;  // 0..1023
    int j = idx >> 4, kq = idx & 15, k0 = kq * 8;
    float v[8];
#pragma unroll
    for (int u = 0; u < 8; u++) {
      int k = k0 + u;
      v[u] = (k < 64) ? Ws[k * 64 + j] : Wn[(k - 64) * 64 + j];
    }
    uint4 r;
    r.x = packbf2(v[0], v[1]);
    r.y = packbf2(v[2], v[3]);
    r.z = packbf2(v[4], v[5]);
    r.w = packbf2(v[6], v[7]);
    *(uint4*)&wtbf[j * 128 + k0] = r;
    if (idx < 64) biasf[idx] = bs[idx] + bn[idx];
  }
}

// ---------- pass 2: per-bucket column scan (block per bucket) ----------
__global__ __launch_bounds__(P) void scan_cols(int* __restrict__ hist,
                                               int* __restrict__ colTot, int nb) {
  int b = blockIdx.x;
  int t = threadIdx.x;  // chunk index p
  int v = hist[(size_t)t * nb + b];
  int lane = t & 63, w = t >> 6;  // 8 waves
  int inc = v;
  for (int o = 1; o < 64; o <<= 1) {
    int u = __shfl_up(inc, o, 64);
    if (lane >= o) inc += u;
  }
  __shared__ int wsum[P / 64];
  if (lane == 63) wsum[w] = inc;
  __syncthreads();
  int woff = 0;
  for (int i = 0; i < w; i++) woff += wsum[i];
  hist[(size_t)t * nb + b] = woff + inc - v;  // exclusive within column
  if (t == P - 1) colTot[b] = woff + inc;     // column total
}

// ---------- pass 3: partition edges (inline bucket-base scan) ----------
__global__ __launch_bounds__(256) void part_k(const int* __restrict__ ei,
                                              const int* __restrict__ offs,
                                              const int* __restrict__ colTot,
                                              int* __restrict__ bucketBase,
                                              int* __restrict__ pairs,
                                              int E, int chunk, int nb) {
  __shared__ int cur[NBMAX];
  __shared__ int sBase[NBMAX];
  __shared__ int wsum[4];
  int p = blockIdx.x;
  int t = threadIdx.x;
  // exclusive scan of colTot[0..nb) : thread t owns entries 4t..4t+3
  int c0 = (4 * t + 0 < nb) ? colTot[4 * t + 0] : 0;
  int c1 = (4 * t + 1 < nb) ? colTot[4 * t + 1] : 0;
  int c2 = (4 * t + 2 < nb) ? colTot[4 * t + 2] : 0;
  int c3 = (4 * t + 3 < nb) ? colTot[4 * t + 3] : 0;
  int s = c0 + c1 + c2 + c3;
  int lane = t & 63, w = t >> 6;
  int inc = s;
  for (int o = 1; o < 64; o <<= 1) {
    int u = __shfl_up(inc, o, 64);
    if (lane >= o) inc += u;
  }
  if (lane == 63) wsum[w] = inc;
  __syncthreads();
  int woff = 0;
  for (int i = 0; i < w; i++) woff += wsum[i];
  int e0 = woff + inc - s;
  sBase[4 * t + 0] = e0;
  sBase[4 * t + 1] = e0 + c0;
  sBase[4 * t + 2] = e0 + c0 + c1;
  sBase[4 * t + 3] = e0 + c0 + c1 + c2;
  if (p == 0) {
    if (4 * t + 0 < nb) bucketBase[4 * t + 0] = e0;
    if (4 * t + 1 < nb) bucketBase[4 * t + 1] = e0 + c0;
    if (4 * t + 2 < nb) bucketBase[4 * t + 2] = e0 + c0 + c1;
    if (4 * t + 3 < nb) bucketBase[4 * t + 3] = e0 + c0 + c1 + c2;
    if (t == 255) bucketBase[nb] = woff + inc;  // == E
  }
  __syncthreads();
  for (int i = t; i < nb; i += 256) cur[i] = offs[p * nb + i] + sBase[i];
  __syncthreads();
  int st = p * chunk, en = min(E, st + chunk);
  for (int i = st + t; i < en; i += 256) {
    int src = ei[i];
    int dst = ei[E + i];
    int pos = atomicAdd(&cur[dst >> 7], 1);
    pairs[pos] = src | ((dst & (BN - 1)) << 20);  // src < 2^20
  }
}

// ---------- pass 4: per-bucket counting sort in LDS -> CSR ----------
// Final write is the PRE-SHIFTED byte offset (src*128) for k_agg.
__global__ __launch_bounds__(256) void sort_k(int* __restrict__ pairs,
                                              const int* __restrict__ bucketBase,
                                              int* __restrict__ rowPtr,
                                              int N, int E) {
  __shared__ int stage[SORTCAP];
  __shared__ int cnt[BN];
  __shared__ int off[BN];
  __shared__ int wtot[2];
  int b = blockIdx.x;
  int st = bucketBase[b], en = bucketBase[b + 1];
  int len = en - st;
  if (len > SORTCAP) len = SORTCAP;
  int t = threadIdx.x;
  if (t < BN) cnt[t] = 0;
  __syncthreads();
  for (int i = t; i < len; i += 256) {
    int pp = pairs[st + i];
    stage[i] = pp;
    atomicAdd(&cnt[pp >> 20], 1);
  }
  __syncthreads();
  int v = (t < BN) ? cnt[t] : 0;
  int inc = v;
  for (int o = 1; o < 64; o <<= 1) {
    int u = __shfl_up(inc, o, 64);
    if ((t & 63) >= o) inc += u;
  }
  if ((t & 63) == 63 && (t >> 6) < 2) wtot[t >> 6] = inc;
  __syncthreads();
  if (t < BN) off[t] = ((t >= 64) ? wtot[0] : 0) + inc - v;
  __syncthreads();
  int nodeBase = b * BN;
  if (t < BN && nodeBase + t < N) rowPtr[nodeBase + t] = st + off[t];
  if (b == 0 && t == 0) rowPtr[N] = E;
  __syncthreads();
  for (int i = t; i < len; i += 256) {
    int pp = stage[i];
    int pos = atomicAdd(&off[pp >> 20], 1);
    pairs[st + pos] = (pp & 0xFFFFF) << 7;  // byte offset into xbf
  }
}

// ---------- pass 5: aggregate (wave per node, bf16 gather, f2 pk accum) -----
// lane = (g = edge-in-quad [0,4), fg = bf16x4 feature group [0,16)).
__global__ __launch_bounds__(256) void k_agg(const unsigned short* __restrict__ xbf,
                                             const int* __restrict__ rowPtr,
                                             const int* __restrict__ soff,
                                             unsigned short* __restrict__ aggbf,
                                             int nBase, int nEnd) {
  int gid = blockIdx.x * blockDim.x + threadIdx.x;
  int lane = threadIdx.x & 63;
  int wave = gid >> 6;
  int nwaves = (gridDim.x * blockDim.x) >> 6;
  int g = lane >> 4, fg = lane & 15;
  const char* xb = (const char*)xbf;
  for (int n = nBase + wave; n < nEnd; n += nwaves) {
    int st = rowPtr[n], en = rowPtr[n + 1];
    f2_t e0 = {0.f, 0.f}, o0v = {0.f, 0.f};
    f2_t e1 = {0.f, 0.f}, o1v = {0.f, 0.f};
    f2_t e2 = {0.f, 0.f}, o2v = {0.f, 0.f};
    f2_t e3 = {0.f, 0.f}, o3v = {0.f, 0.f};
    int i = st;
    for (; i + 16 <= en; i += 16) {
      int b0 = soff[i + g];
      int b1 = soff[i + 4 + g];
      int b2 = soff[i + 8 + g];
      int b3 = soff[i + 12 + g];
      uint2 v0 = *(const uint2*)(xb + (size_t)(unsigned)b0 + fg * 8);
      uint2 v1 = *(const uint2*)(xb + (size_t)(unsigned)b1 + fg * 8);
      uint2 v2 = *(const uint2*)(xb + (size_t)(unsigned)b2 + fg * 8);
      uint2 v3 = *(const uint2*)(xb + (size_t)(unsigned)b3 + fg * 8);
      f2_t p;
      p.x = __uint_as_float(v0.x << 16); p.y = __uint_as_float(v0.y << 16); e0 += p;
      p.x = __uint_as_float(v0.x & 0xFFFF0000u); p.y = __uint_as_float(v0.y & 0xFFFF0000u); o0v += p;
      p.x = __uint_as_float(v1.x << 16); p.y = __uint_as_float(v1.y << 16); e1 += p;
      p.x = __uint_as_float(v1.x & 0xFFFF0000u); p.y = __uint_as_float(v1.y & 0xFFFF0000u); o1v += p;
      p.x = __uint_as_float(v2.x << 16); p.y = __uint_as_float(v2.y << 16); e2 += p;
      p.x = __uint_as_float(v2.x & 0xFFFF0000u); p.y = __uint_as_float(v2.y & 0xFFFF0000u); o2v += p;
      p.x = __uint_as_float(v3.x << 16); p.y = __uint_as_float(v3.y << 16); e3 += p;
      p.x = __uint_as_float(v3.x & 0xFFFF0000u); p.y = __uint_as_float(v3.y & 0xFFFF0000u); o3v += p;
    }
    for (; i < en; i += 4) {
      int idx = i + g;
      if (idx < en) {
        int bo = soff[idx];
        uint2 v = *(const uint2*)(xb + (size_t)(unsigned)bo + fg * 8);
        f2_t p;
        p.x = __uint_as_float(v.x << 16); p.y = __uint_as_float(v.y << 16); e0 += p;
        p.x = __uint_as_float(v.x & 0xFFFF0000u); p.y = __uint_as_float(v.y & 0xFFFF0000u); o0v += p;
      }
    }
    f2_t accE = (e0 + e1) + (e2 + e3);
    f2_t accO = (o0v + o1v) + (o2v + o3v);
    f2_t tm;
    tm.x = __shfl_xor(accE.x, 16, 64); tm.y = __shfl_xor(accE.y, 16, 64); accE += tm;
    tm.x = __shfl_xor(accO.x, 16, 64); tm.y = __shfl_xor(accO.y, 16, 64); accO += tm;
    tm.x = __shfl_xor(accE.x, 32, 64); tm.y = __shfl_xor(accE.y, 32, 64); accE += tm;
    tm.x = __shfl_xor(accO.x, 32, 64); tm.y = __shfl_xor(accO.y, 32, 64); accO += tm;
    int len = en - st;
    float inv = 1.f / (float)(len > 0 ? len : 1);
    if (g == 0) {
      uint2 r;
      r.x = packbf2(accE.x * inv, accO.x * inv);  // f0,f1
      r.y = packbf2(accE.y * inv, accO.y * inv);  // f2,f3
      ((uint2*)(aggbf + (size_t)n * D))[fg] = r;
    }
  }
}

// ---------- pass 6: MFMA bf16 GEMM + bias + relu ----------
__global__ __launch_bounds__(256) void k_gemm(const unsigned short* __restrict__ xbf,
                                              const unsigned short* __restrict__ aggbf,
                                              const unsigned short* __restrict__ wtbf,
                                              const float* __restrict__ biasf,
                                              float* __restrict__ out, int ntiles) {
  __shared__ unsigned short sWT[64 * KP];
  __shared__ unsigned short sA[4 * 16 * KP];

  int t = threadIdx.x;
#pragma unroll
  for (int i = 0; i < 4; i++) {  // 1024 uint4 copies, coalesced
    int idx = i * 256 + t;
    int row = idx >> 4, q = idx & 15;
    *(uint4*)&sWT[row * KP + q * 8] = *(const uint4*)&wtbf[row * 128 + q * 8];
  }
  __syncthreads();

  int w = t >> 6, lane = t & 63;
  int row = lane & 15, part = lane >> 4;  // staging roles (part also = quad)
  unsigned short* myA = &sA[w * 16 * KP];

  for (int tile = blockIdx.x * 4 + w; tile < ntiles; tile += gridDim.x * 4) {
    int n0 = tile * 16;
    {
      const unsigned short* srcp =
          (part < 2) ? (xbf + (size_t)(n0 + row) * D + (part & 1) * 32)
                     : (aggbf + (size_t)(n0 + row) * D + (part & 1) * 32);
      const uint4* s4 = (const uint4*)srcp;
      uint4* d4 = (uint4*)&myA[row * KP + part * 32];
      d4[0] = s4[0];
      d4[1] = s4[1];
      d4[2] = s4[2];
      d4[3] = s4[3];
    }
    bf8_t af[4];
#pragma unroll
    for (int kt = 0; kt < 4; kt++)
      af[kt] = *(const bf8_t*)&myA[row * KP + kt * 32 + part * 8];
#pragma unroll
    for (int jt = 0; jt < 4; jt++) {
      f4_t acc = {0.f, 0.f, 0.f, 0.f};
#pragma unroll
      for (int kt = 0; kt < 4; kt++) {
        bf8_t bfr = *(const bf8_t*)&sWT[(jt * 16 + row) * KP + kt * 32 + part * 8];
        acc = __builtin_amdgcn_mfma_f32_16x16x32_bf16(af[kt], bfr, acc, 0, 0, 0);
      }
      int col = jt * 16 + row;
      float bias = biasf[col];
#pragma unroll
      for (int r = 0; r < 4; r++) {
        float v = acc[r] + bias;
        v = v > 0.f ? v : 0.f;
        out[(size_t)(n0 + part * 4 + r) * D + col] = v;
      }
    }
  }
}

extern "C" void kernel_launch(void* const* d_in, const int* in_sizes, int n_in,
                              void* d_out, int out_size, void* d_ws, size_t ws_size,
                              hipStream_t stream) {
  const float* x      = (const float*)d_in[0];
  const int*   ei     = (const int*)d_in[1];
  const float* Wself  = (const float*)d_in[2];
  const float* bself  = (const float*)d_in[3];
  const float* Wneigh = (const float*)d_in[4];
  const float* bneigh = (const float*)d_in[5];

  int N = in_sizes[0] / D;
  int E = in_sizes[1] / 2;
  int nb = (N + BN - 1) / BN;        // 782
  int chunk = (E + P - 1) / P;       // 3125
  int ntiles = (N + 15) / 16;        // 6250

  // workspace layout (16B-aligned blocks, in order)
  unsigned short* xbf   = (unsigned short*)d_ws;          // N*D bf16
  unsigned short* aggbf = xbf + (size_t)N * D;            // N*D bf16
  unsigned short* wtbf  = aggbf + (size_t)N * D;          // 64*128 bf16
  float* biasf    = (float*)(wtbf + 64 * 128);            // 64 f
  int* pairs      = (int*)(biasf + 64);                   // E ints
  int* hist       = pairs + E;                            // P*nb ints
  int* colTot     = hist + (size_t)P * nb;                // nb ints
  int* bucketBase = colTot + nb;                          // nb+1 ints
  int* rowPtr     = bucketBase + nb + 1;                  // N+1 ints

  pre_k<<<P + CVTB + WTB, 256, 0, stream>>>(ei + E, hist, E, chunk, nb,
                                            x, xbf, N * D / 4,
                                            Wself, Wneigh, bself, bneigh,
                                            wtbf, biasf);
  scan_cols<<<nb, P, 0, stream>>>(hist, colTot, nb);
  part_k<<<P, 256, 0, stream>>>(ei, hist, colTot, bucketBase, pairs, E, chunk, nb);
  sort_k<<<nb, 256, 0, stream>>>(pairs, bucketBase, rowPtr, N, E);
  int half = N / 2;
  k_agg<<<3125, 256, 0, stream>>>(xbf, rowPtr, pairs, aggbf, 0, half);
  k_agg<<<3125, 256, 0, stream>>>(xbf, rowPtr, pairs, aggbf, half, N);
  k_gemm<<<1563, 256, 0, stream>>>(xbf, aggbf, wtbf, biasf, (float*)d_out, ntiles);
}